// Round 5
// baseline (363.324 us; speedup 1.0000x reference)
//
#include <hip/hip_runtime.h>
#include <hip/hip_bf16.h>
#include <math.h>

#define T_TOK 2048
#define HDIM  2048
#define IDIM  1408
#define NG    2816          // 2*IDIM
#define NEXP  8
#define NPAIR (T_TOK*2)
#define RPAD  6144          // 4096 rows + per-expert pad-to-256 (max 6136)

typedef __attribute__((ext_vector_type(4))) float  f32x4;
typedef __attribute__((ext_vector_type(4))) short  s16x4;
typedef __attribute__((ext_vector_type(8))) short  s16x8;
typedef __attribute__((ext_vector_type(8))) __bf16 bf16x8;

__device__ __forceinline__ short f2bf(float f) {
  union { float f; unsigned u; } v; v.f = f;
  unsigned r = v.u + 0x7FFFu + ((v.u >> 16) & 1u);   // RNE
  return (short)(r >> 16);
}

__device__ __forceinline__ float bf2f(short s) {
  union { unsigned u; float f; } v; v.u = ((unsigned)(unsigned short)s) << 16;
  return v.f;
}

__device__ __forceinline__ void gload_lds16(const void* g, void* l) {
  __builtin_amdgcn_global_load_lds((const __attribute__((address_space(1))) unsigned int*)g,
                                   (__attribute__((address_space(3))) unsigned int*)l,
                                   16, 0, 0);
}

// ---------------- router ----------------
__global__ void router_kernel(const float* __restrict__ hs, const float* __restrict__ rw,
                              int* __restrict__ pair_e, float* __restrict__ pair_w,
                              int* __restrict__ pair_pos, int* __restrict__ counts) {
  int wid = threadIdx.x >> 6, lane = threadIdx.x & 63;
  int t = blockIdx.x * 4 + wid;
  float acc[NEXP];
#pragma unroll
  for (int e = 0; e < NEXP; e++) acc[e] = 0.f;
  const float* h = hs + (size_t)t * HDIM;
  for (int k = lane; k < HDIM; k += 64) {
    float x = h[k];
    f32x4 w0 = *(const f32x4*)(rw + (size_t)k * NEXP);
    f32x4 w1 = *(const f32x4*)(rw + (size_t)k * NEXP + 4);
#pragma unroll
    for (int e = 0; e < 4; e++) { acc[e] += x * w0[e]; acc[e + 4] += x * w1[e]; }
  }
#pragma unroll
  for (int e = 0; e < NEXP; e++)
#pragma unroll
    for (int off = 32; off > 0; off >>= 1)
      acc[e] += __shfl_xor(acc[e], off, 64);
  if (lane == 0) {
    int i1 = 0; float v1 = acc[0];
#pragma unroll
    for (int e = 1; e < NEXP; e++) if (acc[e] > v1) { v1 = acc[e]; i1 = e; }
    int i2 = -1; float v2 = -3.4e38f;
#pragma unroll
    for (int e = 0; e < NEXP; e++) if (e != i1 && acc[e] > v2) { v2 = acc[e]; i2 = e; }
    float w2 = 1.f / (1.f + expf(v1 - v2));
    float w1 = 1.f - w2;
    int p1 = atomicAdd(&counts[i1], 1);
    int p2 = atomicAdd(&counts[i2], 1);
    pair_e[2*t]   = i1; pair_w[2*t]   = w1; pair_pos[2*t]   = p1;
    pair_e[2*t+1] = i2; pair_w[2*t+1] = w2; pair_pos[2*t+1] = p2;
  }
}

__global__ void prefix_kernel(const int* __restrict__ counts, int* __restrict__ offs) {
  if (threadIdx.x == 0) {
    int s = 0;
    for (int e = 0; e < NEXP; e++) { offs[e] = s; s += (counts[e] + 255) & ~255; }
    offs[NEXP] = s;
  }
}

__global__ void rowmap_kernel(const int* __restrict__ pair_e, const float* __restrict__ pair_w,
                              const int* __restrict__ pair_pos, const int* __restrict__ offs,
                              int* __restrict__ row_token, float* __restrict__ row_weight,
                              int* __restrict__ tok2row) {
  int p = blockIdx.x * 256 + threadIdx.x;
  if (p >= NPAIR) return;
  int e = pair_e[p];
  int row = offs[e] + pair_pos[p];
  row_token[row] = p >> 1;
  row_weight[row] = pair_w[p];
  tok2row[p] = row;
}

// -------- gather tokens -> compact bf16 A, pre-swizzled by (row&7) --------
__global__ __launch_bounds__(256) void gather_kernel(const float* __restrict__ hs,
                                                     const int* __restrict__ row_token,
                                                     short* __restrict__ A_c) {
  int r = blockIdx.x;
  int tok = row_token[r];
  int t = threadIdx.x;
  if (tok < 0) {           // pad row must be zeros
    *(s16x8*)&A_c[(size_t)r * HDIM + t * 8] = (s16x8)0;
    return;
  }
  const float* src = hs + (size_t)tok * HDIM + t * 8;
  f32x4 v0 = *(const f32x4*)src;
  f32x4 v1 = *(const f32x4*)(src + 4);
  s16x8 o;
#pragma unroll
  for (int j = 0; j < 4; j++) { o[j] = f2bf(v0[j]); o[4 + j] = f2bf(v1[j]); }
  int dstg = (t & ~7) | ((t & 7) ^ (r & 7));
  *(s16x8*)&A_c[(size_t)r * HDIM + dstg * 8] = o;
}

// -------- W fp32 [e][K][N] -> bf16 [e][N][K], XOR-swizzled by (n&7) -------
__global__ __launch_bounds__(256) void convert_w_kernel(
    const float* __restrict__ src, short* __restrict__ dst, int K, int N, int e_base) {
  int e = blockIdx.z + e_base;
  src += (size_t)e * K * N;
  dst += (size_t)blockIdx.z * K * N;
  int n0 = blockIdx.x * 64, k0 = blockIdx.y * 64;
  __shared__ short tile[64 * 76];
  int tid = threadIdx.x;
#pragma unroll
  for (int it = 0; it < 4; it++) {
    int s = tid + it * 256;
    int kk = s >> 4, nn = (s & 15) * 4;
    f32x4 v = *(const f32x4*)(src + (size_t)(k0 + kk) * N + n0 + nn);
    s16x4 b;
#pragma unroll
    for (int j = 0; j < 4; j++) b[j] = f2bf(v[j]);
    *(s16x4*)&tile[kk * 76 + nn] = b;
  }
  __syncthreads();
#pragma unroll
  for (int it = 0; it < 2; it++) {
    int s = tid + it * 256;
    int n = s >> 3, g = s & 7;
    int gs = g ^ (n & 7);
    s16x8 o;
#pragma unroll
    for (int j = 0; j < 8; j++) o[j] = tile[(gs * 8 + j) * 76 + n];
    *(s16x8*)&dst[(size_t)(n0 + n) * K + k0 + g * 8] = o;
  }
}

// ===== gate_up GEMM: 8-phase-style, 256M x (128g+128u)N x BK64, 512 thr ===
__global__ __launch_bounds__(512, 2) void gateup_kernel(
    const short* __restrict__ A_c, const short* __restrict__ W,
    const int* __restrict__ offs, short* __restrict__ S,
    int e_only, size_t w_e_stride) {
  // bijective XCD-chunked remap: grid 264 = 8 x 33, wgid consecutive on XCD,
  // nb fastest within a rowblock (A-panel reuse in XCD L2)
  int orig = blockIdx.x;
  int wgid = (orig & 7) * 33 + (orig >> 3);
  int rblk = wgid / 11, nb = wgid % 11;
  int rb = rblk * 256;
  if (rb >= offs[NEXP]) return;
  int e = 0;
#pragma unroll
  for (int i = 1; i < NEXP; i++) e += (rb >= offs[i]);
  if (e_only >= 0 && e != e_only) return;
  const short* Wb = W + (e_only >= 0 ? 0 : (size_t)e * w_e_stride);
  const short* Ar = A_c + (size_t)rb * HDIM;
  const short* Bg = Wb + (size_t)(nb * 128) * HDIM;
  const short* Bu = Wb + (size_t)(IDIM + nb * 128) * HDIM;

  __shared__ short As[2][256 * 64];       // 64 KB
  __shared__ short Bs[2][256 * 64];       // 64 KB: rows 0-127 gate, 128-255 up
  int tid = threadIdx.x, lane = tid & 63, wid = tid >> 6;
  int wm = wid >> 2, wn = wid & 3;
  int lm = lane & 15, lg = lane >> 4;

  f32x4 acc[8][4];                        // [mi][nf]; nf 0,1=gate 2,3=up
#pragma unroll
  for (int a = 0; a < 8; a++)
#pragma unroll
    for (int b = 0; b < 4; b++) acc[a][b] = (f32x4)0.f;

  auto STAGE = [&](int buf, int kt) {     // 8 gload_lds per thread
    int k0 = kt * 64;
#pragma unroll
    for (int it = 0; it < 4; it++) {
      int idx = tid + it * 512;
      gload_lds16(Ar + (size_t)(idx >> 3) * HDIM + k0 + (idx & 7) * 8, &As[buf][idx * 8]);
    }
#pragma unroll
    for (int it = 0; it < 2; it++) {
      int idx = tid + it * 512;
      gload_lds16(Bg + (size_t)(idx >> 3) * HDIM + k0 + (idx & 7) * 8, &Bs[buf][idx * 8]);
      gload_lds16(Bu + (size_t)(idx >> 3) * HDIM + k0 + (idx & 7) * 8, &Bs[buf][8192 + idx * 8]);
    }
  };

  STAGE(0, 0);
  const int NT = HDIM / 64;               // 32
  bf16x8 bq[4];
#pragma unroll 1
  for (int kt = 0; kt < NT; kt++) {
    int cur = kt & 1;
#pragma unroll
    for (int p = 0; p < 4; p++) {
      if (p == 0) {
        if (kt + 1 < NT) {
          STAGE(cur ^ 1, kt + 1);
          asm volatile("s_waitcnt vmcnt(8)" ::: "memory");  // tile kt landed
        } else {
          asm volatile("s_waitcnt vmcnt(0)" ::: "memory");
        }
      }
      __builtin_amdgcn_s_barrier();
      __builtin_amdgcn_sched_barrier(0);
      const int ks = p >> 1, mih = p & 1;
      bf16x8 av[4];
#pragma unroll
      for (int mi4 = 0; mi4 < 4; mi4++) {
        int m = wm * 128 + (mih * 4 + mi4) * 16 + lm;
        av[mi4] = *(const bf16x8*)&As[cur][m * 64 + (((ks * 4 + lg) ^ (m & 7)) * 8)];
      }
      if (mih == 0) {
#pragma unroll
        for (int nf = 0; nf < 4; nf++) {
          int rbq = (nf >> 1) * 128 + wn * 32 + (nf & 1) * 16 + lm;
          bq[nf] = *(const bf16x8*)&Bs[cur][rbq * 64 + (((ks * 4 + lg) ^ (rbq & 7)) * 8)];
        }
      }
      __builtin_amdgcn_s_setprio(1);
#pragma unroll
      for (int mi4 = 0; mi4 < 4; mi4++)
#pragma unroll
        for (int nf = 0; nf < 4; nf++)
          acc[mih * 4 + mi4][nf] =
              __builtin_amdgcn_mfma_f32_16x16x32_bf16(av[mi4], bq[nf], acc[mih * 4 + mi4][nf], 0, 0, 0);
      __builtin_amdgcn_s_setprio(0);
      __builtin_amdgcn_sched_barrier(0);
      __builtin_amdgcn_s_barrier();
    }
  }
  // epilogue: SiLU(gate)*up -> S (bf16, granule-swizzled by rg&7 per 64 cols)
#pragma unroll
  for (int mi = 0; mi < 8; mi++)
#pragma unroll
    for (int nfg = 0; nfg < 2; nfg++)
#pragma unroll
      for (int j = 0; j < 4; j++) {
        int row = wm * 128 + mi * 16 + lg * 4 + j;
        int rg = rb + row;
        int scol = nb * 128 + wn * 32 + nfg * 16 + lm;
        int base = scol & ~63, o = scol & 63;
        int dc = (((o >> 3) ^ (rg & 7)) << 3) | (o & 7);
        float g = acc[mi][nfg][j], u = acc[mi][nfg + 2][j];
        float sv = (g / (1.f + expf(-g))) * u;
        S[(size_t)rg * IDIM + base + dc] = f2bf(sv);
      }
}

// ===== down GEMM: 8-phase-style, 256M x 256N x BK64, 512 thr ==============
__global__ __launch_bounds__(512, 2) void down_kernel(
    const short* __restrict__ S, const short* __restrict__ W,
    const int* __restrict__ offs, short* __restrict__ Sout,
    int e_only, size_t w_e_stride) {
  int orig = blockIdx.x;                  // grid 192 = 8 x 24
  int wgid = (orig & 7) * 24 + (orig >> 3);
  int rblk = wgid / 8, nb = wgid % 8;
  int rb = rblk * 256;
  if (rb >= offs[NEXP]) return;
  int e = 0;
#pragma unroll
  for (int i = 1; i < NEXP; i++) e += (rb >= offs[i]);
  if (e_only >= 0 && e != e_only) return;
  const short* Ar = S + (size_t)rb * IDIM;
  const short* Bw = W + (e_only >= 0 ? 0 : (size_t)e * w_e_stride) + (size_t)(nb * 256) * IDIM;

  __shared__ short As[2][256 * 64];
  __shared__ short Bs[2][256 * 64];
  int tid = threadIdx.x, lane = tid & 63, wid = tid >> 6;
  int wm = wid >> 2, wn = wid & 3;
  int lm = lane & 15, lg = lane >> 4;

  f32x4 acc[8][4];
#pragma unroll
  for (int a = 0; a < 8; a++)
#pragma unroll
    for (int b = 0; b < 4; b++) acc[a][b] = (f32x4)0.f;

  auto STAGE = [&](int buf, int kt) {     // 8 gload_lds per thread
    int k0 = kt * 64;
#pragma unroll
    for (int it = 0; it < 4; it++) {
      int idx = tid + it * 512;
      gload_lds16(Ar + (size_t)(idx >> 3) * IDIM + k0 + (idx & 7) * 8, &As[buf][idx * 8]);
      gload_lds16(Bw + (size_t)(idx >> 3) * IDIM + k0 + (idx & 7) * 8, &Bs[buf][idx * 8]);
    }
  };

  STAGE(0, 0);
  const int NT = IDIM / 64;               // 22
  bf16x8 bq[4];
#pragma unroll 1
  for (int kt = 0; kt < NT; kt++) {
    int cur = kt & 1;
#pragma unroll
    for (int p = 0; p < 4; p++) {
      if (p == 0) {
        if (kt + 1 < NT) {
          STAGE(cur ^ 1, kt + 1);
          asm volatile("s_waitcnt vmcnt(8)" ::: "memory");
        } else {
          asm volatile("s_waitcnt vmcnt(0)" ::: "memory");
        }
      }
      __builtin_amdgcn_s_barrier();
      __builtin_amdgcn_sched_barrier(0);
      const int ks = p >> 1, mih = p & 1;
      bf16x8 av[4];
#pragma unroll
      for (int mi4 = 0; mi4 < 4; mi4++) {
        int m = wm * 128 + (mih * 4 + mi4) * 16 + lm;
        av[mi4] = *(const bf16x8*)&As[cur][m * 64 + (((ks * 4 + lg) ^ (m & 7)) * 8)];
      }
      if (mih == 0) {
#pragma unroll
        for (int nf = 0; nf < 4; nf++) {
          int rbq = wn * 64 + nf * 16 + lm;
          bq[nf] = *(const bf16x8*)&Bs[cur][rbq * 64 + (((ks * 4 + lg) ^ (rbq & 7)) * 8)];
        }
      }
      __builtin_amdgcn_s_setprio(1);
#pragma unroll
      for (int mi4 = 0; mi4 < 4; mi4++)
#pragma unroll
        for (int nf = 0; nf < 4; nf++)
          acc[mih * 4 + mi4][nf] =
              __builtin_amdgcn_mfma_f32_16x16x32_bf16(av[mi4], bq[nf], acc[mih * 4 + mi4][nf], 0, 0, 0);
      __builtin_amdgcn_s_setprio(0);
      __builtin_amdgcn_sched_barrier(0);
      __builtin_amdgcn_s_barrier();
    }
  }
  // epilogue: plain bf16 stores (combine does the weighted sum)
#pragma unroll
  for (int mi = 0; mi < 8; mi++)
#pragma unroll
    for (int nf = 0; nf < 4; nf++)
#pragma unroll
      for (int j = 0; j < 4; j++) {
        int row = wm * 128 + mi * 16 + lg * 4 + j;
        int col = nb * 256 + wn * 64 + nf * 16 + lm;
        Sout[(size_t)(rb + row) * HDIM + col] = f2bf(acc[mi][nf][j]);
      }
}

// ------------- combine: out[t] = w1*Sout[r1] + w2*Sout[r2] ---------------
__global__ __launch_bounds__(256) void combine_kernel(
    const short* __restrict__ Sout, const int* __restrict__ tok2row,
    const float* __restrict__ row_weight, float* __restrict__ out) {
  int t = blockIdx.x;
  int r1 = tok2row[2 * t], r2 = tok2row[2 * t + 1];
  float w1 = row_weight[r1], w2 = row_weight[r2];
  int c = threadIdx.x * 8;
  s16x8 a = *(const s16x8*)&Sout[(size_t)r1 * HDIM + c];
  s16x8 b = *(const s16x8*)&Sout[(size_t)r2 * HDIM + c];
  float* o = out + (size_t)t * HDIM + c;
#pragma unroll
  for (int j = 0; j < 8; j++) o[j] = w1 * bf2f(a[j]) + w2 * bf2f(b[j]);
}

extern "C" void kernel_launch(void* const* d_in, const int* in_sizes, int n_in,
                              void* d_out, int out_size, void* d_ws, size_t ws_size,
                              hipStream_t stream) {
  const float* hs  = (const float*)d_in[0];
  const float* rw  = (const float*)d_in[1];
  const float* guw = (const float*)d_in[2];
  const float* dw  = (const float*)d_in[3];
  float* out = (float*)d_out;

  char* ws = (char*)d_ws;
  size_t off = 0;
  auto take = [&](size_t b) { size_t p = off; off = (off + b + 255) & ~(size_t)255; return p; };
  size_t s_off      = take((size_t)RPAD * IDIM * 2);   // 17.3 MB
  int*   counts     = (int*)(ws + take(32 * 4));
  int*   offs       = (int*)(ws + take(16 * 4));
  int*   pair_e     = (int*)(ws + take(NPAIR * 4));
  float* pair_w     = (float*)(ws + take(NPAIR * 4));
  int*   pair_pos   = (int*)(ws + take(NPAIR * 4));
  int*   row_token  = (int*)(ws + take(RPAD * 4));
  float* row_weight = (float*)(ws + take(RPAD * 4));
  int*   tok2row    = (int*)(ws + take(NPAIR * 4));
  size_t ac_off  = take((size_t)RPAD * HDIM * 2);      // 25.2 MB (A_c; Sout overlays later)
  size_t wg_off  = off;                                // Wg; Wd overlays later

  short* S    = (short*)(ws + s_off);
  short* A_c  = (short*)(ws + ac_off);
  short* Sout = (short*)(ws + ac_off);                 // overlays A_c (dead after gateup)

  const size_t WG_BYTES = (size_t)NEXP * NG * HDIM * 2;   // 92.3 MB
  bool full = ws_size >= wg_off + WG_BYTES;

  hipMemsetAsync(counts, 0, 32 * 4, stream);
  hipMemsetAsync(row_token, 0xFF, RPAD * 4, stream);

  router_kernel<<<T_TOK / 4, 256, 0, stream>>>(hs, rw, pair_e, pair_w, pair_pos, counts);
  prefix_kernel<<<1, 64, 0, stream>>>(counts, offs);
  rowmap_kernel<<<NPAIR / 256, 256, 0, stream>>>(pair_e, pair_w, pair_pos, offs,
                                                 row_token, row_weight, tok2row);
  gather_kernel<<<RPAD, 256, 0, stream>>>(hs, row_token, A_c);

  if (full) {
    short* Wg = (short*)(ws + wg_off);
    short* Wd = (short*)(ws + wg_off);      // overlays Wg (dead after gateup)
    convert_w_kernel<<<dim3(NG / 64, HDIM / 64, NEXP), 256, 0, stream>>>(guw, Wg, HDIM, NG, 0);
    gateup_kernel<<<264, 512, 0, stream>>>(A_c, Wg, offs, S, -1, (size_t)NG * HDIM);
    convert_w_kernel<<<dim3(HDIM / 64, IDIM / 64, NEXP), 256, 0, stream>>>(dw, Wd, IDIM, HDIM, 0);
    down_kernel<<<192, 512, 0, stream>>>(S, Wd, offs, Sout, -1, (size_t)HDIM * IDIM);
    combine_kernel<<<T_TOK, 256, 0, stream>>>(Sout, tok2row, row_weight, out);
  } else {
    short* slot = (short*)(ws + wg_off);    // 11.5 MB slot
    for (int e = 0; e < NEXP; e++) {
      convert_w_kernel<<<dim3(NG / 64, HDIM / 64, 1), 256, 0, stream>>>(guw, slot, HDIM, NG, e);
      gateup_kernel<<<264, 512, 0, stream>>>(A_c, slot, offs, S, e, 0);
    }
    for (int e = 0; e < NEXP; e++) {
      convert_w_kernel<<<dim3(HDIM / 64, IDIM / 64, 1), 256, 0, stream>>>(dw, slot, IDIM, HDIM, e);
      down_kernel<<<192, 512, 0, stream>>>(S, slot, offs, Sout, e, 0);
    }
    combine_kernel<<<T_TOK, 256, 0, stream>>>(Sout, tok2row, row_weight, out);
  }
}

// Round 6
// 355.838 us; speedup vs baseline: 1.0210x; 1.0210x over previous
//
#include <hip/hip_runtime.h>
#include <hip/hip_bf16.h>
#include <math.h>

#define T_TOK 2048
#define HDIM  2048
#define IDIM  1408
#define NG    2816          // 2*IDIM
#define NEXP  8
#define NPAIR (T_TOK*2)
#define RPAD  6144          // 4096 rows + per-expert pad-to-256 (max 6136)

typedef __attribute__((ext_vector_type(4))) float  f32x4;
typedef __attribute__((ext_vector_type(4))) short  s16x4;
typedef __attribute__((ext_vector_type(8))) short  s16x8;
typedef __attribute__((ext_vector_type(8))) __bf16 bf16x8;

__device__ __forceinline__ short f2bf(float f) {
  union { float f; unsigned u; } v; v.f = f;
  unsigned r = v.u + 0x7FFFu + ((v.u >> 16) & 1u);   // RNE
  return (short)(r >> 16);
}

__device__ __forceinline__ float bf2f(short s) {
  union { unsigned u; float f; } v; v.u = ((unsigned)(unsigned short)s) << 16;
  return v.f;
}

__device__ __forceinline__ void gload_lds16(const void* g, void* l) {
  __builtin_amdgcn_global_load_lds((const __attribute__((address_space(1))) unsigned int*)g,
                                   (__attribute__((address_space(3))) unsigned int*)l,
                                   16, 0, 0);
}

// ---------------- router ----------------
__global__ void router_kernel(const float* __restrict__ hs, const float* __restrict__ rw,
                              int* __restrict__ pair_e, float* __restrict__ pair_w,
                              int* __restrict__ pair_pos, int* __restrict__ counts) {
  int wid = threadIdx.x >> 6, lane = threadIdx.x & 63;
  int t = blockIdx.x * 4 + wid;
  float acc[NEXP];
#pragma unroll
  for (int e = 0; e < NEXP; e++) acc[e] = 0.f;
  const float* h = hs + (size_t)t * HDIM;
  for (int k = lane; k < HDIM; k += 64) {
    float x = h[k];
    f32x4 w0 = *(const f32x4*)(rw + (size_t)k * NEXP);
    f32x4 w1 = *(const f32x4*)(rw + (size_t)k * NEXP + 4);
#pragma unroll
    for (int e = 0; e < 4; e++) { acc[e] += x * w0[e]; acc[e + 4] += x * w1[e]; }
  }
#pragma unroll
  for (int e = 0; e < NEXP; e++)
#pragma unroll
    for (int off = 32; off > 0; off >>= 1)
      acc[e] += __shfl_xor(acc[e], off, 64);
  if (lane == 0) {
    int i1 = 0; float v1 = acc[0];
#pragma unroll
    for (int e = 1; e < NEXP; e++) if (acc[e] > v1) { v1 = acc[e]; i1 = e; }
    int i2 = -1; float v2 = -3.4e38f;
#pragma unroll
    for (int e = 0; e < NEXP; e++) if (e != i1 && acc[e] > v2) { v2 = acc[e]; i2 = e; }
    float w2 = 1.f / (1.f + expf(v1 - v2));
    float w1 = 1.f - w2;
    int p1 = atomicAdd(&counts[i1], 1);
    int p2 = atomicAdd(&counts[i2], 1);
    pair_e[2*t]   = i1; pair_w[2*t]   = w1; pair_pos[2*t]   = p1;
    pair_e[2*t+1] = i2; pair_w[2*t+1] = w2; pair_pos[2*t+1] = p2;
  }
}

__global__ void prefix_kernel(const int* __restrict__ counts, int* __restrict__ offs) {
  if (threadIdx.x == 0) {
    int s = 0;
    for (int e = 0; e < NEXP; e++) { offs[e] = s; s += (counts[e] + 255) & ~255; }
    offs[NEXP] = s;
  }
}

__global__ void rowmap_kernel(const int* __restrict__ pair_e, const float* __restrict__ pair_w,
                              const int* __restrict__ pair_pos, const int* __restrict__ offs,
                              int* __restrict__ row_token, float* __restrict__ row_weight,
                              int* __restrict__ tok2row) {
  int p = blockIdx.x * 256 + threadIdx.x;
  if (p >= NPAIR) return;
  int e = pair_e[p];
  int row = offs[e] + pair_pos[p];
  row_token[row] = p >> 1;
  row_weight[row] = pair_w[p];
  tok2row[p] = row;
}

// -------- gather tokens -> compact bf16 A, pre-swizzled by (row&7) --------
__global__ __launch_bounds__(256) void gather_kernel(const float* __restrict__ hs,
                                                     const int* __restrict__ row_token,
                                                     short* __restrict__ A_c) {
  int r = blockIdx.x;
  int tok = row_token[r];
  int t = threadIdx.x;
  if (tok < 0) {           // pad row must be zeros
    *(s16x8*)&A_c[(size_t)r * HDIM + t * 8] = (s16x8)0;
    return;
  }
  const float* src = hs + (size_t)tok * HDIM + t * 8;
  f32x4 v0 = *(const f32x4*)src;
  f32x4 v1 = *(const f32x4*)(src + 4);
  s16x8 o;
#pragma unroll
  for (int j = 0; j < 4; j++) { o[j] = f2bf(v0[j]); o[4 + j] = f2bf(v1[j]); }
  int dstg = (t & ~7) | ((t & 7) ^ (r & 7));
  *(s16x8*)&A_c[(size_t)r * HDIM + dstg * 8] = o;
}

// -------- W fp32 [e][K][N] -> bf16 [e][N][K], XOR-swizzled by (n&7) -------
__global__ __launch_bounds__(256) void convert_w_kernel(
    const float* __restrict__ src, short* __restrict__ dst, int K, int N, int e_base) {
  int e = blockIdx.z + e_base;
  src += (size_t)e * K * N;
  dst += (size_t)blockIdx.z * K * N;
  int n0 = blockIdx.x * 64, k0 = blockIdx.y * 64;
  __shared__ short tile[64 * 76];
  int tid = threadIdx.x;
#pragma unroll
  for (int it = 0; it < 4; it++) {
    int s = tid + it * 256;
    int kk = s >> 4, nn = (s & 15) * 4;
    f32x4 v = *(const f32x4*)(src + (size_t)(k0 + kk) * N + n0 + nn);
    s16x4 b;
#pragma unroll
    for (int j = 0; j < 4; j++) b[j] = f2bf(v[j]);
    *(s16x4*)&tile[kk * 76 + nn] = b;
  }
  __syncthreads();
#pragma unroll
  for (int it = 0; it < 2; it++) {
    int s = tid + it * 256;
    int n = s >> 3, g = s & 7;
    int gs = g ^ (n & 7);
    s16x8 o;
#pragma unroll
    for (int j = 0; j < 8; j++) o[j] = tile[(gs * 8 + j) * 76 + n];
    *(s16x8*)&dst[(size_t)(n0 + n) * K + k0 + g * 8] = o;
  }
}

// ===== gate_up GEMM: 4-phase pipelined, 256M x (128g+128u)N x BK64 ========
__global__ __launch_bounds__(512, 2) void gateup_kernel(
    const short* __restrict__ A_c, const short* __restrict__ W,
    const int* __restrict__ offs, short* __restrict__ S,
    int e_only, size_t w_e_stride) {
  int orig = blockIdx.x;                  // grid 264 = 8 x 33
  int wgid = (orig & 7) * 33 + (orig >> 3);
  int rblk = wgid / 11, nb = wgid % 11;
  int rb = rblk * 256;
  if (rb >= offs[NEXP]) return;
  int e = 0;
#pragma unroll
  for (int i = 1; i < NEXP; i++) e += (rb >= offs[i]);
  if (e_only >= 0 && e != e_only) return;
  const short* Wb = W + (e_only >= 0 ? 0 : (size_t)e * w_e_stride);
  const short* Ar = A_c + (size_t)rb * HDIM;
  const short* Bg = Wb + (size_t)(nb * 128) * HDIM;
  const short* Bu = Wb + (size_t)(IDIM + nb * 128) * HDIM;

  __shared__ short As[2][256 * 64];       // 64 KB
  __shared__ short Bs[2][256 * 64];       // 64 KB: rows 0-127 gate, 128-255 up
  int tid = threadIdx.x, lane = tid & 63, wid = tid >> 6;
  int wm = wid >> 2, wn = wid & 3;
  int lm = lane & 15, lg = lane >> 4;

  f32x4 acc[8][4];                        // [mi][nf]; nf 0,1=gate 2,3=up
#pragma unroll
  for (int a = 0; a < 8; a++)
#pragma unroll
    for (int b = 0; b < 4; b++) acc[a][b] = (f32x4)0.f;

  auto STAGE = [&](int buf, int kt) {     // 8 gload_lds per thread
    int k0 = kt * 64;
#pragma unroll
    for (int it = 0; it < 4; it++) {
      int idx = tid + it * 512;
      gload_lds16(Ar + (size_t)(idx >> 3) * HDIM + k0 + (idx & 7) * 8, &As[buf][idx * 8]);
    }
#pragma unroll
    for (int it = 0; it < 2; it++) {
      int idx = tid + it * 512;
      gload_lds16(Bg + (size_t)(idx >> 3) * HDIM + k0 + (idx & 7) * 8, &Bs[buf][idx * 8]);
      gload_lds16(Bu + (size_t)(idx >> 3) * HDIM + k0 + (idx & 7) * 8, &Bs[buf][8192 + idx * 8]);
    }
  };
  auto READ_A = [&](bf16x8* dst, int buf, int mih, int ks) {
#pragma unroll
    for (int mi4 = 0; mi4 < 4; mi4++) {
      int m = wm * 128 + (mih * 4 + mi4) * 16 + lm;
      dst[mi4] = *(const bf16x8*)&As[buf][m * 64 + (((ks * 4 + lg) ^ (m & 7)) * 8)];
    }
  };
  auto READ_B = [&](bf16x8* dst, int buf, int ks) {
#pragma unroll
    for (int nf = 0; nf < 4; nf++) {
      int rbq = (nf >> 1) * 128 + wn * 32 + (nf & 1) * 16 + lm;
      dst[nf] = *(const bf16x8*)&Bs[buf][rbq * 64 + (((ks * 4 + lg) ^ (rbq & 7)) * 8)];
    }
  };
  auto MFMA16 = [&](const bf16x8* a, const bf16x8* b, int mih) {
    __builtin_amdgcn_s_setprio(1);
#pragma unroll
    for (int mi4 = 0; mi4 < 4; mi4++)
#pragma unroll
      for (int nf = 0; nf < 4; nf++)
        acc[mih * 4 + mi4][nf] =
            __builtin_amdgcn_mfma_f32_16x16x32_bf16(a[mi4], b[nf], acc[mih * 4 + mi4][nf], 0, 0, 0);
    __builtin_amdgcn_s_setprio(0);
  };

  STAGE(0, 0);
  const int NT = HDIM / 64;               // 32
#pragma unroll 1
  for (int kt = 0; kt < NT; kt++) {
    int cur = kt & 1;
    bf16x8 a0[4], a1[4], b0[4], b1[4];
    // ---- phase 0: (ks0, mih0) ----
    if (kt + 1 < NT) {
      STAGE(cur ^ 1, kt + 1);
      asm volatile("s_waitcnt vmcnt(8)" ::: "memory");   // tile kt landed
    } else {
      asm volatile("s_waitcnt vmcnt(0)" ::: "memory");
    }
    __builtin_amdgcn_s_barrier();
    READ_A(a0, cur, 0, 0); READ_B(b0, cur, 0);
    MFMA16(a0, b0, 0);
    READ_A(a1, cur, 1, 0);                // for phase 1 (latency hides in barrier)
    __builtin_amdgcn_s_barrier();
    // ---- phase 1: (ks0, mih1) ----
    MFMA16(a1, b0, 1);
    READ_A(a0, cur, 0, 1); READ_B(b1, cur, 1);   // for phase 2
    __builtin_amdgcn_s_barrier();
    // ---- phase 2: (ks1, mih0) ----
    MFMA16(a0, b1, 0);
    READ_A(a1, cur, 1, 1);                // for phase 3
    __builtin_amdgcn_s_barrier();
    // ---- phase 3: (ks1, mih1) ----
    MFMA16(a1, b1, 1);
    __builtin_amdgcn_s_barrier();
  }
  // epilogue: SiLU(gate)*up -> S (bf16, granule-swizzled by rg&7 per 64 cols)
#pragma unroll
  for (int mi = 0; mi < 8; mi++)
#pragma unroll
    for (int nfg = 0; nfg < 2; nfg++)
#pragma unroll
      for (int j = 0; j < 4; j++) {
        int row = wm * 128 + mi * 16 + lg * 4 + j;
        int rg = rb + row;
        int scol = nb * 128 + wn * 32 + nfg * 16 + lm;
        int base = scol & ~63, o = scol & 63;
        int dc = (((o >> 3) ^ (rg & 7)) << 3) | (o & 7);
        float g = acc[mi][nfg][j], u = acc[mi][nfg + 2][j];
        float sv = (g / (1.f + expf(-g))) * u;
        S[(size_t)rg * IDIM + base + dc] = f2bf(sv);
      }
}

// ===== down GEMM: 4-phase pipelined, 256M x 256N x BK64 ===================
__global__ __launch_bounds__(512, 2) void down_kernel(
    const short* __restrict__ S, const short* __restrict__ W,
    const int* __restrict__ offs, short* __restrict__ Sout,
    int e_only, size_t w_e_stride) {
  int orig = blockIdx.x;                  // grid 192 = 8 x 24
  int wgid = (orig & 7) * 24 + (orig >> 3);
  int rblk = wgid / 8, nb = wgid % 8;
  int rb = rblk * 256;
  if (rb >= offs[NEXP]) return;
  int e = 0;
#pragma unroll
  for (int i = 1; i < NEXP; i++) e += (rb >= offs[i]);
  if (e_only >= 0 && e != e_only) return;
  const short* Ar = S + (size_t)rb * IDIM;
  const short* Bw = W + (e_only >= 0 ? 0 : (size_t)e * w_e_stride) + (size_t)(nb * 256) * IDIM;

  __shared__ short As[2][256 * 64];
  __shared__ short Bs[2][256 * 64];
  int tid = threadIdx.x, lane = tid & 63, wid = tid >> 6;
  int wm = wid >> 2, wn = wid & 3;
  int lm = lane & 15, lg = lane >> 4;

  f32x4 acc[8][4];
#pragma unroll
  for (int a = 0; a < 8; a++)
#pragma unroll
    for (int b = 0; b < 4; b++) acc[a][b] = (f32x4)0.f;

  auto STAGE = [&](int buf, int kt) {     // 8 gload_lds per thread
    int k0 = kt * 64;
#pragma unroll
    for (int it = 0; it < 4; it++) {
      int idx = tid + it * 512;
      gload_lds16(Ar + (size_t)(idx >> 3) * IDIM + k0 + (idx & 7) * 8, &As[buf][idx * 8]);
      gload_lds16(Bw + (size_t)(idx >> 3) * IDIM + k0 + (idx & 7) * 8, &Bs[buf][idx * 8]);
    }
  };
  auto READ_A = [&](bf16x8* dst, int buf, int mih, int ks) {
#pragma unroll
    for (int mi4 = 0; mi4 < 4; mi4++) {
      int m = wm * 128 + (mih * 4 + mi4) * 16 + lm;
      dst[mi4] = *(const bf16x8*)&As[buf][m * 64 + (((ks * 4 + lg) ^ (m & 7)) * 8)];
    }
  };
  auto READ_B = [&](bf16x8* dst, int buf, int ks) {
#pragma unroll
    for (int nf = 0; nf < 4; nf++) {
      int rbq = wn * 64 + nf * 16 + lm;
      dst[nf] = *(const bf16x8*)&Bs[buf][rbq * 64 + (((ks * 4 + lg) ^ (rbq & 7)) * 8)];
    }
  };
  auto MFMA16 = [&](const bf16x8* a, const bf16x8* b, int mih) {
    __builtin_amdgcn_s_setprio(1);
#pragma unroll
    for (int mi4 = 0; mi4 < 4; mi4++)
#pragma unroll
      for (int nf = 0; nf < 4; nf++)
        acc[mih * 4 + mi4][nf] =
            __builtin_amdgcn_mfma_f32_16x16x32_bf16(a[mi4], b[nf], acc[mih * 4 + mi4][nf], 0, 0, 0);
    __builtin_amdgcn_s_setprio(0);
  };

  STAGE(0, 0);
  const int NT = IDIM / 64;               // 22
#pragma unroll 1
  for (int kt = 0; kt < NT; kt++) {
    int cur = kt & 1;
    bf16x8 a0[4], a1[4], b0[4], b1[4];
    if (kt + 1 < NT) {
      STAGE(cur ^ 1, kt + 1);
      asm volatile("s_waitcnt vmcnt(8)" ::: "memory");
    } else {
      asm volatile("s_waitcnt vmcnt(0)" ::: "memory");
    }
    __builtin_amdgcn_s_barrier();
    READ_A(a0, cur, 0, 0); READ_B(b0, cur, 0);
    MFMA16(a0, b0, 0);
    READ_A(a1, cur, 1, 0);
    __builtin_amdgcn_s_barrier();
    MFMA16(a1, b0, 1);
    READ_A(a0, cur, 0, 1); READ_B(b1, cur, 1);
    __builtin_amdgcn_s_barrier();
    MFMA16(a0, b1, 0);
    READ_A(a1, cur, 1, 1);
    __builtin_amdgcn_s_barrier();
    MFMA16(a1, b1, 1);
    __builtin_amdgcn_s_barrier();
  }
  // epilogue: plain bf16 stores (combine does the weighted sum)
#pragma unroll
  for (int mi = 0; mi < 8; mi++)
#pragma unroll
    for (int nf = 0; nf < 4; nf++)
#pragma unroll
      for (int j = 0; j < 4; j++) {
        int row = wm * 128 + mi * 16 + lg * 4 + j;
        int col = nb * 256 + wn * 64 + nf * 16 + lm;
        Sout[(size_t)(rb + row) * HDIM + col] = f2bf(acc[mi][nf][j]);
      }
}

// ------------- combine: out[t] = w1*Sout[r1] + w2*Sout[r2] ---------------
__global__ __launch_bounds__(256) void combine_kernel(
    const short* __restrict__ Sout, const int* __restrict__ tok2row,
    const float* __restrict__ row_weight, float* __restrict__ out) {
  int t = blockIdx.x;
  int r1 = tok2row[2 * t], r2 = tok2row[2 * t + 1];
  float w1 = row_weight[r1], w2 = row_weight[r2];
  int c = threadIdx.x * 8;
  s16x8 a = *(const s16x8*)&Sout[(size_t)r1 * HDIM + c];
  s16x8 b = *(const s16x8*)&Sout[(size_t)r2 * HDIM + c];
  float* o = out + (size_t)t * HDIM + c;
#pragma unroll
  for (int j = 0; j < 8; j++) o[j] = w1 * bf2f(a[j]) + w2 * bf2f(b[j]);
}

extern "C" void kernel_launch(void* const* d_in, const int* in_sizes, int n_in,
                              void* d_out, int out_size, void* d_ws, size_t ws_size,
                              hipStream_t stream) {
  const float* hs  = (const float*)d_in[0];
  const float* rw  = (const float*)d_in[1];
  const float* guw = (const float*)d_in[2];
  const float* dw  = (const float*)d_in[3];
  float* out = (float*)d_out;

  char* ws = (char*)d_ws;
  size_t off = 0;
  auto take = [&](size_t b) { size_t p = off; off = (off + b + 255) & ~(size_t)255; return p; };
  size_t s_off      = take((size_t)RPAD * IDIM * 2);   // 17.3 MB
  int*   counts     = (int*)(ws + take(32 * 4));
  int*   offs       = (int*)(ws + take(16 * 4));
  int*   pair_e     = (int*)(ws + take(NPAIR * 4));
  float* pair_w     = (float*)(ws + take(NPAIR * 4));
  int*   pair_pos   = (int*)(ws + take(NPAIR * 4));
  int*   row_token  = (int*)(ws + take(RPAD * 4));
  float* row_weight = (float*)(ws + take(RPAD * 4));
  int*   tok2row    = (int*)(ws + take(NPAIR * 4));
  size_t ac_off  = take((size_t)RPAD * HDIM * 2);      // 25.2 MB (A_c; Sout overlays later)
  size_t wg_off  = off;                                // Wg; Wd overlays later

  short* S    = (short*)(ws + s_off);
  short* A_c  = (short*)(ws + ac_off);
  short* Sout = (short*)(ws + ac_off);                 // overlays A_c (dead after gateup)

  const size_t WG_BYTES = (size_t)NEXP * NG * HDIM * 2;   // 92.3 MB
  bool full = ws_size >= wg_off + WG_BYTES;

  hipMemsetAsync(counts, 0, 32 * 4, stream);
  hipMemsetAsync(row_token, 0xFF, RPAD * 4, stream);

  router_kernel<<<T_TOK / 4, 256, 0, stream>>>(hs, rw, pair_e, pair_w, pair_pos, counts);
  prefix_kernel<<<1, 64, 0, stream>>>(counts, offs);
  rowmap_kernel<<<NPAIR / 256, 256, 0, stream>>>(pair_e, pair_w, pair_pos, offs,
                                                 row_token, row_weight, tok2row);
  gather_kernel<<<RPAD, 256, 0, stream>>>(hs, row_token, A_c);

  if (full) {
    short* Wg = (short*)(ws + wg_off);
    short* Wd = (short*)(ws + wg_off);      // overlays Wg (dead after gateup)
    convert_w_kernel<<<dim3(NG / 64, HDIM / 64, NEXP), 256, 0, stream>>>(guw, Wg, HDIM, NG, 0);
    gateup_kernel<<<264, 512, 0, stream>>>(A_c, Wg, offs, S, -1, (size_t)NG * HDIM);
    convert_w_kernel<<<dim3(HDIM / 64, IDIM / 64, NEXP), 256, 0, stream>>>(dw, Wd, IDIM, HDIM, 0);
    down_kernel<<<192, 512, 0, stream>>>(S, Wd, offs, Sout, -1, (size_t)HDIM * IDIM);
    combine_kernel<<<T_TOK, 256, 0, stream>>>(Sout, tok2row, row_weight, out);
  } else {
    short* slot = (short*)(ws + wg_off);    // 11.5 MB slot
    for (int e = 0; e < NEXP; e++) {
      convert_w_kernel<<<dim3(NG / 64, HDIM / 64, 1), 256, 0, stream>>>(guw, slot, HDIM, NG, e);
      gateup_kernel<<<264, 512, 0, stream>>>(A_c, slot, offs, S, e, 0);
    }
    for (int e = 0; e < NEXP; e++) {
      convert_w_kernel<<<dim3(HDIM / 64, IDIM / 64, 1), 256, 0, stream>>>(dw, slot, IDIM, HDIM, e);
      down_kernel<<<192, 512, 0, stream>>>(S, slot, offs, Sout, e, 0);
    }
    combine_kernel<<<T_TOK, 256, 0, stream>>>(Sout, tok2row, row_weight, out);
  }
}

// Round 7
// 288.855 us; speedup vs baseline: 1.2578x; 1.2319x over previous
//
#include <hip/hip_runtime.h>
#include <hip/hip_bf16.h>
#include <math.h>

#define T_TOK 2048
#define HDIM  2048
#define IDIM  1408
#define NG    2816          // 2*IDIM
#define NEXP  8
#define NPAIR (T_TOK*2)
#define RPAD  6144          // 4096 rows + per-expert pad-to-256 (max 6136)

typedef __attribute__((ext_vector_type(4))) float  f32x4;
typedef __attribute__((ext_vector_type(4))) short  s16x4;
typedef __attribute__((ext_vector_type(8))) short  s16x8;
typedef __attribute__((ext_vector_type(8))) __bf16 bf16x8;

__device__ __forceinline__ short f2bf(float f) {
  union { float f; unsigned u; } v; v.f = f;
  unsigned r = v.u + 0x7FFFu + ((v.u >> 16) & 1u);   // RNE
  return (short)(r >> 16);
}

__device__ __forceinline__ float bf2f(short s) {
  union { unsigned u; float f; } v; v.u = ((unsigned)(unsigned short)s) << 16;
  return v.f;
}

__device__ __forceinline__ void gload_lds16(const void* g, void* l) {
  __builtin_amdgcn_global_load_lds((const __attribute__((address_space(1))) unsigned int*)g,
                                   (__attribute__((address_space(3))) unsigned int*)l,
                                   16, 0, 0);
}

// ---------------- router ----------------
__global__ void router_kernel(const float* __restrict__ hs, const float* __restrict__ rw,
                              int* __restrict__ pair_e, float* __restrict__ pair_w,
                              int* __restrict__ pair_pos, int* __restrict__ counts) {
  int wid = threadIdx.x >> 6, lane = threadIdx.x & 63;
  int t = blockIdx.x * 4 + wid;
  float acc[NEXP];
#pragma unroll
  for (int e = 0; e < NEXP; e++) acc[e] = 0.f;
  const float* h = hs + (size_t)t * HDIM;
  for (int k = lane; k < HDIM; k += 64) {
    float x = h[k];
    f32x4 w0 = *(const f32x4*)(rw + (size_t)k * NEXP);
    f32x4 w1 = *(const f32x4*)(rw + (size_t)k * NEXP + 4);
#pragma unroll
    for (int e = 0; e < 4; e++) { acc[e] += x * w0[e]; acc[e + 4] += x * w1[e]; }
  }
#pragma unroll
  for (int e = 0; e < NEXP; e++)
#pragma unroll
    for (int off = 32; off > 0; off >>= 1)
      acc[e] += __shfl_xor(acc[e], off, 64);
  if (lane == 0) {
    int i1 = 0; float v1 = acc[0];
#pragma unroll
    for (int e = 1; e < NEXP; e++) if (acc[e] > v1) { v1 = acc[e]; i1 = e; }
    int i2 = -1; float v2 = -3.4e38f;
#pragma unroll
    for (int e = 0; e < NEXP; e++) if (e != i1 && acc[e] > v2) { v2 = acc[e]; i2 = e; }
    float w2 = 1.f / (1.f + expf(v1 - v2));
    float w1 = 1.f - w2;
    int p1 = atomicAdd(&counts[i1], 1);
    int p2 = atomicAdd(&counts[i2], 1);
    pair_e[2*t]   = i1; pair_w[2*t]   = w1; pair_pos[2*t]   = p1;
    pair_e[2*t+1] = i2; pair_w[2*t+1] = w2; pair_pos[2*t+1] = p2;
  }
}

__global__ void prefix_kernel(const int* __restrict__ counts, int* __restrict__ offs) {
  if (threadIdx.x == 0) {
    int s = 0;
    for (int e = 0; e < NEXP; e++) { offs[e] = s; s += (counts[e] + 255) & ~255; }
    offs[NEXP] = s;
  }
}

__global__ void rowmap_kernel(const int* __restrict__ pair_e, const float* __restrict__ pair_w,
                              const int* __restrict__ pair_pos, const int* __restrict__ offs,
                              int* __restrict__ row_token, float* __restrict__ row_weight,
                              int* __restrict__ tok2row) {
  int p = blockIdx.x * 256 + threadIdx.x;
  if (p >= NPAIR) return;
  int e = pair_e[p];
  int row = offs[e] + pair_pos[p];
  row_token[row] = p >> 1;
  row_weight[row] = pair_w[p];
  tok2row[p] = row;
}

// -------- gather tokens -> compact bf16 A, pre-swizzled by (row&7) --------
__global__ __launch_bounds__(256) void gather_kernel(const float* __restrict__ hs,
                                                     const int* __restrict__ row_token,
                                                     short* __restrict__ A_c) {
  int r = blockIdx.x;
  int tok = row_token[r];
  int t = threadIdx.x;
  if (tok < 0) {           // pad row must be zeros
    *(s16x8*)&A_c[(size_t)r * HDIM + t * 8] = (s16x8)0;
    return;
  }
  const float* src = hs + (size_t)tok * HDIM + t * 8;
  f32x4 v0 = *(const f32x4*)src;
  f32x4 v1 = *(const f32x4*)(src + 4);
  s16x8 o;
#pragma unroll
  for (int j = 0; j < 4; j++) { o[j] = f2bf(v0[j]); o[4 + j] = f2bf(v1[j]); }
  int dstg = (t & ~7) | ((t & 7) ^ (r & 7));
  *(s16x8*)&A_c[(size_t)r * HDIM + dstg * 8] = o;
}

// ===== gate_up GEMM, fused fp32 weights: 256M x (128g+128u)N x BK64 =======
// A: bf16 A_c via gload_lds (double-buffered). B: fp32 reg-staged + cvt +
// conflict-free transposed ds_write (single buffer). 2 barriers/K-step,
// counted vmcnt (loads one full tile ahead).
__global__ __launch_bounds__(512, 2) void gateup_kernel(
    const short* __restrict__ A_c, const float* __restrict__ guw,
    const int* __restrict__ offs, short* __restrict__ S) {
  int nb = blockIdx.x;                  // 0..10
  int rb = blockIdx.y * 256;
  if (rb >= offs[NEXP]) return;
  int e = 0;
#pragma unroll
  for (int i = 1; i < NEXP; i++) e += (rb >= offs[i]);
  const float* Wsrc = guw + (size_t)e * HDIM * NG;
  const short* Ar = A_c + (size_t)rb * HDIM;

  __shared__ short bufA[2][256 * 64];   // 2 x 32 KB
  __shared__ short bufB[256 * 64];      // 32 KB: n 0-127 gate, 128-255 up
  int tid = threadIdx.x, lane = tid & 63, wid = tid >> 6;
  int wm = wid >> 2, wn = wid & 3;
  int lm = lane & 15, lg = lane >> 4;

  // B staging map: thread -> 8 consecutive n (oct), 4 consecutive k (kq)
  int oct = tid >> 4, kq = tid & 15;
  int n0 = oct * 8;
  int col = (n0 < 128) ? (nb * 128 + n0) : (IDIM + nb * 128 + (n0 - 128));
  const float* Bp = Wsrc + col;

  f32x4 acc[8][4];                      // [mi][nf]; nf 0,1=gate 2,3=up
#pragma unroll
  for (int a = 0; a < 8; a++)
#pragma unroll
    for (int b = 0; b < 4; b++) acc[a][b] = (f32x4)0.f;

  f32x4 va[4], vb[4];                   // B prefetch regs (32 floats)

  auto STAGE_A = [&](int buf, int kt) {
    int k0 = kt * 64;
#pragma unroll
    for (int it = 0; it < 4; it++) {
      int idx = tid + it * 512;
      gload_lds16(Ar + (size_t)(idx >> 3) * HDIM + k0 + (idx & 7) * 8, &bufA[buf][idx * 8]);
    }
  };
  auto LOAD_B = [&](int kt) {
    const float* p = Bp + (size_t)(kt * 64 + kq * 4) * NG;
#pragma unroll
    for (int j = 0; j < 4; j++) {
      va[j] = *(const f32x4*)(p + (size_t)j * NG);
      vb[j] = *(const f32x4*)(p + (size_t)j * NG + 4);
    }
  };
  auto WRITE_B = [&]() {                // cvt + transposed write, conflict-free
    int gc = kq >> 1, half = kq & 1;
#pragma unroll
    for (int i = 0; i < 8; i++) {
      int n = n0 + i;
      s16x4 w;
#pragma unroll
      for (int j = 0; j < 4; j++) w[j] = f2bf(i < 4 ? va[j][i] : vb[j][i - 4]);
      *(s16x4*)&bufB[n * 64 + ((gc ^ (n & 7)) * 8) + half * 4] = w;
    }
  };

  STAGE_A(0, 0);                        // A(0): 4 gload_lds
  LOAD_B(0);                            // B(0): 8 loads
  const int NT = HDIM / 64;             // 32
#pragma unroll 1
  for (int kt = 0; kt < NT; kt++) {
    int cur = kt & 1;
    if (kt + 1 < NT) {
      STAGE_A(cur ^ 1, kt + 1);         // dest free since prev end-barrier
      asm volatile("s_waitcnt vmcnt(4)" ::: "memory");   // A(kt)+B(kt) done
    } else {
      asm volatile("s_waitcnt vmcnt(0)" ::: "memory");
    }
    WRITE_B();
    if (kt + 1 < NT) LOAD_B(kt + 1);    // in flight across both barriers
    asm volatile("s_waitcnt lgkmcnt(0)" ::: "memory");
    __builtin_amdgcn_s_barrier();       // staging visible to all waves
#pragma unroll
    for (int ks = 0; ks < 2; ks++) {
      bf16x8 a[8], b[4];
#pragma unroll
      for (int mi = 0; mi < 8; mi++) {
        int m = wm * 128 + mi * 16 + lm;
        a[mi] = *(const bf16x8*)&bufA[cur][m * 64 + (((ks * 4 + lg) ^ (m & 7)) * 8)];
      }
#pragma unroll
      for (int nf = 0; nf < 4; nf++) {
        int n = (nf >> 1) * 128 + wn * 32 + (nf & 1) * 16 + lm;
        b[nf] = *(const bf16x8*)&bufB[n * 64 + (((ks * 4 + lg) ^ (n & 7)) * 8)];
      }
      __builtin_amdgcn_s_setprio(1);
#pragma unroll
      for (int mi = 0; mi < 8; mi++)
#pragma unroll
        for (int nf = 0; nf < 4; nf++)
          acc[mi][nf] = __builtin_amdgcn_mfma_f32_16x16x32_bf16(a[mi], b[nf], acc[mi][nf], 0, 0, 0);
      __builtin_amdgcn_s_setprio(0);
    }
    asm volatile("s_waitcnt lgkmcnt(0)" ::: "memory");
    __builtin_amdgcn_s_barrier();       // reads retired; buffers free
  }
  // epilogue: SiLU(gate)*up -> S (bf16, granule-swizzled by rg&7 per 64 cols)
#pragma unroll
  for (int mi = 0; mi < 8; mi++)
#pragma unroll
    for (int nfg = 0; nfg < 2; nfg++)
#pragma unroll
      for (int j = 0; j < 4; j++) {
        int row = wm * 128 + mi * 16 + lg * 4 + j;
        int rg = rb + row;
        int scol = nb * 128 + wn * 32 + nfg * 16 + lm;
        int base = scol & ~63, o = scol & 63;
        int dc = (((o >> 3) ^ (rg & 7)) << 3) | (o & 7);
        float g = acc[mi][nfg][j], u = acc[mi][nfg + 2][j];
        float sv = (g / (1.f + expf(-g))) * u;
        S[(size_t)rg * IDIM + base + dc] = f2bf(sv);
      }
}

// ===== down GEMM, fused fp32 weights: 256M x 256N x BK64 ==================
__global__ __launch_bounds__(512, 2) void down_kernel(
    const short* __restrict__ S, const float* __restrict__ dw,
    const int* __restrict__ offs, short* __restrict__ Sout) {
  int nb = blockIdx.x;                  // 0..7
  int rb = blockIdx.y * 256;
  if (rb >= offs[NEXP]) return;
  int e = 0;
#pragma unroll
  for (int i = 1; i < NEXP; i++) e += (rb >= offs[i]);
  const float* Wsrc = dw + (size_t)e * IDIM * HDIM;
  const short* Ar = S + (size_t)rb * IDIM;

  __shared__ short bufA[2][256 * 64];
  __shared__ short bufB[256 * 64];
  int tid = threadIdx.x, lane = tid & 63, wid = tid >> 6;
  int wm = wid >> 2, wn = wid & 3;
  int lm = lane & 15, lg = lane >> 4;

  int oct = tid >> 4, kq = tid & 15;
  int n0 = oct * 8;
  const float* Bp = Wsrc + nb * 256 + n0;

  f32x4 acc[8][4];
#pragma unroll
  for (int a = 0; a < 8; a++)
#pragma unroll
    for (int b = 0; b < 4; b++) acc[a][b] = (f32x4)0.f;

  f32x4 va[4], vb[4];

  auto STAGE_A = [&](int buf, int kt) {
    int k0 = kt * 64;
#pragma unroll
    for (int it = 0; it < 4; it++) {
      int idx = tid + it * 512;
      gload_lds16(Ar + (size_t)(idx >> 3) * IDIM + k0 + (idx & 7) * 8, &bufA[buf][idx * 8]);
    }
  };
  auto LOAD_B = [&](int kt) {
    const float* p = Bp + (size_t)(kt * 64 + kq * 4) * HDIM;
#pragma unroll
    for (int j = 0; j < 4; j++) {
      va[j] = *(const f32x4*)(p + (size_t)j * HDIM);
      vb[j] = *(const f32x4*)(p + (size_t)j * HDIM + 4);
    }
  };
  auto WRITE_B = [&]() {
    int gc = kq >> 1, half = kq & 1;
#pragma unroll
    for (int i = 0; i < 8; i++) {
      int n = n0 + i;
      s16x4 w;
#pragma unroll
      for (int j = 0; j < 4; j++) w[j] = f2bf(i < 4 ? va[j][i] : vb[j][i - 4]);
      *(s16x4*)&bufB[n * 64 + ((gc ^ (n & 7)) * 8) + half * 4] = w;
    }
  };

  STAGE_A(0, 0);
  LOAD_B(0);
  const int NT = IDIM / 64;             // 22
#pragma unroll 1
  for (int kt = 0; kt < NT; kt++) {
    int cur = kt & 1;
    if (kt + 1 < NT) {
      STAGE_A(cur ^ 1, kt + 1);
      asm volatile("s_waitcnt vmcnt(4)" ::: "memory");
    } else {
      asm volatile("s_waitcnt vmcnt(0)" ::: "memory");
    }
    WRITE_B();
    if (kt + 1 < NT) LOAD_B(kt + 1);
    asm volatile("s_waitcnt lgkmcnt(0)" ::: "memory");
    __builtin_amdgcn_s_barrier();
#pragma unroll
    for (int ks = 0; ks < 2; ks++) {
      bf16x8 a[8], b[4];
#pragma unroll
      for (int mi = 0; mi < 8; mi++) {
        int m = wm * 128 + mi * 16 + lm;
        a[mi] = *(const bf16x8*)&bufA[cur][m * 64 + (((ks * 4 + lg) ^ (m & 7)) * 8)];
      }
#pragma unroll
      for (int nf = 0; nf < 4; nf++) {
        int n = wn * 64 + nf * 16 + lm;
        b[nf] = *(const bf16x8*)&bufB[n * 64 + (((ks * 4 + lg) ^ (n & 7)) * 8)];
      }
      __builtin_amdgcn_s_setprio(1);
#pragma unroll
      for (int mi = 0; mi < 8; mi++)
#pragma unroll
        for (int nf = 0; nf < 4; nf++)
          acc[mi][nf] = __builtin_amdgcn_mfma_f32_16x16x32_bf16(a[mi], b[nf], acc[mi][nf], 0, 0, 0);
      __builtin_amdgcn_s_setprio(0);
    }
    asm volatile("s_waitcnt lgkmcnt(0)" ::: "memory");
    __builtin_amdgcn_s_barrier();
  }
  // epilogue: plain bf16 stores (combine does the weighted sum)
#pragma unroll
  for (int mi = 0; mi < 8; mi++)
#pragma unroll
    for (int nf = 0; nf < 4; nf++)
#pragma unroll
      for (int j = 0; j < 4; j++) {
        int row = wm * 128 + mi * 16 + lg * 4 + j;
        int col = nb * 256 + wn * 64 + nf * 16 + lm;
        Sout[(size_t)(rb + row) * HDIM + col] = f2bf(acc[mi][nf][j]);
      }
}

// ------------- combine: out[t] = w1*Sout[r1] + w2*Sout[r2] ---------------
__global__ __launch_bounds__(256) void combine_kernel(
    const short* __restrict__ Sout, const int* __restrict__ tok2row,
    const float* __restrict__ row_weight, float* __restrict__ out) {
  int t = blockIdx.x;
  int r1 = tok2row[2 * t], r2 = tok2row[2 * t + 1];
  float w1 = row_weight[r1], w2 = row_weight[r2];
  int c = threadIdx.x * 8;
  s16x8 a = *(const s16x8*)&Sout[(size_t)r1 * HDIM + c];
  s16x8 b = *(const s16x8*)&Sout[(size_t)r2 * HDIM + c];
  float* o = out + (size_t)t * HDIM + c;
#pragma unroll
  for (int j = 0; j < 8; j++) o[j] = w1 * bf2f(a[j]) + w2 * bf2f(b[j]);
}

extern "C" void kernel_launch(void* const* d_in, const int* in_sizes, int n_in,
                              void* d_out, int out_size, void* d_ws, size_t ws_size,
                              hipStream_t stream) {
  const float* hs  = (const float*)d_in[0];
  const float* rw  = (const float*)d_in[1];
  const float* guw = (const float*)d_in[2];
  const float* dw  = (const float*)d_in[3];
  float* out = (float*)d_out;

  char* ws = (char*)d_ws;
  size_t off = 0;
  auto take = [&](size_t b) { size_t p = off; off = (off + b + 255) & ~(size_t)255; return p; };
  size_t s_off      = take((size_t)RPAD * IDIM * 2);   // 17.3 MB
  int*   counts     = (int*)(ws + take(32 * 4));
  int*   offs       = (int*)(ws + take(16 * 4));
  int*   pair_e     = (int*)(ws + take(NPAIR * 4));
  float* pair_w     = (float*)(ws + take(NPAIR * 4));
  int*   pair_pos   = (int*)(ws + take(NPAIR * 4));
  int*   row_token  = (int*)(ws + take(RPAD * 4));
  float* row_weight = (float*)(ws + take(RPAD * 4));
  int*   tok2row    = (int*)(ws + take(NPAIR * 4));
  size_t ac_off     = take((size_t)RPAD * HDIM * 2);   // 25.2 MB
  size_t sout_off   = take((size_t)RPAD * HDIM * 2);   // 25.2 MB

  short* S    = (short*)(ws + s_off);
  short* A_c  = (short*)(ws + ac_off);
  short* Sout = (short*)(ws + sout_off);

  hipMemsetAsync(counts, 0, 32 * 4, stream);
  hipMemsetAsync(row_token, 0xFF, RPAD * 4, stream);

  router_kernel<<<T_TOK / 4, 256, 0, stream>>>(hs, rw, pair_e, pair_w, pair_pos, counts);
  prefix_kernel<<<1, 64, 0, stream>>>(counts, offs);
  rowmap_kernel<<<NPAIR / 256, 256, 0, stream>>>(pair_e, pair_w, pair_pos, offs,
                                                 row_token, row_weight, tok2row);
  gather_kernel<<<RPAD, 256, 0, stream>>>(hs, row_token, A_c);

  gateup_kernel<<<dim3(11, RPAD / 256), 512, 0, stream>>>(A_c, guw, offs, S);
  down_kernel<<<dim3(8, RPAD / 256), 512, 0, stream>>>(S, dw, offs, Sout);
  combine_kernel<<<T_TOK, 256, 0, stream>>>(Sout, tok2row, row_weight, out);
}

// Round 8
// 285.846 us; speedup vs baseline: 1.2711x; 1.0105x over previous
//
#include <hip/hip_runtime.h>
#include <hip/hip_bf16.h>
#include <math.h>

#define T_TOK 2048
#define HDIM  2048
#define IDIM  1408
#define NG    2816          // 2*IDIM
#define NEXP  8
#define NPAIR (T_TOK*2)
#define RPAD  6144          // 4096 rows + per-expert pad-to-256 (max 6136)

typedef __attribute__((ext_vector_type(4))) float  f32x4;
typedef __attribute__((ext_vector_type(4))) short  s16x4;
typedef __attribute__((ext_vector_type(8))) short  s16x8;
typedef __attribute__((ext_vector_type(8))) __bf16 bf16x8;

__device__ __forceinline__ short f2bf(float f) {
  union { float f; unsigned u; } v; v.f = f;
  unsigned r = v.u + 0x7FFFu + ((v.u >> 16) & 1u);   // RNE
  return (short)(r >> 16);
}

__device__ __forceinline__ float bf2f(short s) {
  union { unsigned u; float f; } v; v.u = ((unsigned)(unsigned short)s) << 16;
  return v.f;
}

__device__ __forceinline__ void gload_lds16(const void* g, void* l) {
  __builtin_amdgcn_global_load_lds((const __attribute__((address_space(1))) unsigned int*)g,
                                   (__attribute__((address_space(3))) unsigned int*)l,
                                   16, 0, 0);
}

// ---------------- router ----------------
__global__ void router_kernel(const float* __restrict__ hs, const float* __restrict__ rw,
                              int* __restrict__ pair_e, float* __restrict__ pair_w,
                              int* __restrict__ pair_pos, int* __restrict__ counts) {
  int wid = threadIdx.x >> 6, lane = threadIdx.x & 63;
  int t = blockIdx.x * 4 + wid;
  float acc[NEXP];
#pragma unroll
  for (int e = 0; e < NEXP; e++) acc[e] = 0.f;
  const float* h = hs + (size_t)t * HDIM;
  for (int k = lane; k < HDIM; k += 64) {
    float x = h[k];
    f32x4 w0 = *(const f32x4*)(rw + (size_t)k * NEXP);
    f32x4 w1 = *(const f32x4*)(rw + (size_t)k * NEXP + 4);
#pragma unroll
    for (int e = 0; e < 4; e++) { acc[e] += x * w0[e]; acc[e + 4] += x * w1[e]; }
  }
#pragma unroll
  for (int e = 0; e < NEXP; e++)
#pragma unroll
    for (int off = 32; off > 0; off >>= 1)
      acc[e] += __shfl_xor(acc[e], off, 64);
  if (lane == 0) {
    int i1 = 0; float v1 = acc[0];
#pragma unroll
    for (int e = 1; e < NEXP; e++) if (acc[e] > v1) { v1 = acc[e]; i1 = e; }
    int i2 = -1; float v2 = -3.4e38f;
#pragma unroll
    for (int e = 0; e < NEXP; e++) if (e != i1 && acc[e] > v2) { v2 = acc[e]; i2 = e; }
    float w2 = 1.f / (1.f + expf(v1 - v2));
    float w1 = 1.f - w2;
    int p1 = atomicAdd(&counts[i1], 1);
    int p2 = atomicAdd(&counts[i2], 1);
    pair_e[2*t]   = i1; pair_w[2*t]   = w1; pair_pos[2*t]   = p1;
    pair_e[2*t+1] = i2; pair_w[2*t+1] = w2; pair_pos[2*t+1] = p2;
  }
}

__global__ void prefix_kernel(const int* __restrict__ counts, int* __restrict__ offs) {
  if (threadIdx.x == 0) {
    int s = 0;
    for (int e = 0; e < NEXP; e++) { offs[e] = s; s += (counts[e] + 255) & ~255; }
    offs[NEXP] = s;
  }
}

__global__ void rowmap_kernel(const int* __restrict__ pair_e, const float* __restrict__ pair_w,
                              const int* __restrict__ pair_pos, const int* __restrict__ offs,
                              int* __restrict__ row_token, float* __restrict__ row_weight,
                              int* __restrict__ tok2row) {
  int p = blockIdx.x * 256 + threadIdx.x;
  if (p >= NPAIR) return;
  int e = pair_e[p];
  int row = offs[e] + pair_pos[p];
  row_token[row] = p >> 1;
  row_weight[row] = pair_w[p];
  tok2row[p] = row;
}

// -------- gather tokens -> compact bf16 A, pre-swizzled by (row&7) --------
__global__ __launch_bounds__(256) void gather_kernel(const float* __restrict__ hs,
                                                     const int* __restrict__ row_token,
                                                     short* __restrict__ A_c) {
  int r = blockIdx.x;
  int tok = row_token[r];
  int t = threadIdx.x;
  if (tok < 0) {           // pad row must be zeros
    *(s16x8*)&A_c[(size_t)r * HDIM + t * 8] = (s16x8)0;
    return;
  }
  const float* src = hs + (size_t)tok * HDIM + t * 8;
  f32x4 v0 = *(const f32x4*)src;
  f32x4 v1 = *(const f32x4*)(src + 4);
  s16x8 o;
#pragma unroll
  for (int j = 0; j < 4; j++) { o[j] = f2bf(v0[j]); o[4 + j] = f2bf(v1[j]); }
  int dstg = (t & ~7) | ((t & 7) ^ (r & 7));
  *(s16x8*)&A_c[(size_t)r * HDIM + dstg * 8] = o;
}

// ===== gate_up GEMM, fused fp32 weights: 256M x (128g+128u)N x BK64 =======
// A: bf16 via gload_lds, dbuf, full-iter cover (vmcnt(12) counted).
// B: fp32 reg-staged + cvt + swizzled ds_write into LDS dbuf; WRITE_B for
// tile kt+1 runs inside tile kt's MFMA region (writes bufB[cur^1] while
// MFMAs read bufB[cur]); B global loads get a full iteration of cover.
__global__ __launch_bounds__(512, 2) void gateup_kernel(
    const short* __restrict__ A_c, const float* __restrict__ guw,
    const int* __restrict__ offs, short* __restrict__ S) {
  int nb = blockIdx.x;                  // 0..10
  int rb = blockIdx.y * 256;
  if (rb >= offs[NEXP]) return;
  int e = 0;
#pragma unroll
  for (int i = 1; i < NEXP; i++) e += (rb >= offs[i]);
  const float* Wsrc = guw + (size_t)e * HDIM * NG;
  const short* Ar = A_c + (size_t)rb * HDIM;

  __shared__ short bufA[2][256 * 64];   // 2 x 32 KB
  __shared__ short bufB[2][256 * 64];   // 2 x 32 KB: n 0-127 gate, 128-255 up
  int tid = threadIdx.x, lane = tid & 63, wid = tid >> 6;
  int wm = wid >> 2, wn = wid & 3;
  int lm = lane & 15, lg = lane >> 4;

  // B staging map: thread -> 8 consecutive n (oct), 4 consecutive k (kq)
  int oct = tid >> 4, kq = tid & 15;
  int n0 = oct * 8;
  int col = (n0 < 128) ? (nb * 128 + n0) : (IDIM + nb * 128 + (n0 - 128));
  const float* Bp = Wsrc + col;

  f32x4 acc[8][4];                      // [mi][nf]; nf 0,1=gate 2,3=up
#pragma unroll
  for (int a = 0; a < 8; a++)
#pragma unroll
    for (int b = 0; b < 4; b++) acc[a][b] = (f32x4)0.f;

  f32x4 va[4], vb[4];                   // B prefetch regs (32 floats)

  auto STAGE_A = [&](int buf, int kt) {
    int k0 = kt * 64;
#pragma unroll
    for (int it = 0; it < 4; it++) {
      int idx = tid + it * 512;
      gload_lds16(Ar + (size_t)(idx >> 3) * HDIM + k0 + (idx & 7) * 8, &bufA[buf][idx * 8]);
    }
  };
  auto LOAD_B = [&](int kt) {
    const float* p = Bp + (size_t)(kt * 64 + kq * 4) * NG;
#pragma unroll
    for (int j = 0; j < 4; j++) {
      va[j] = *(const f32x4*)(p + (size_t)j * NG);
      vb[j] = *(const f32x4*)(p + (size_t)j * NG + 4);
    }
  };
  auto WRITE_B = [&](int buf) {         // cvt + transposed swizzled write
    int gc = kq >> 1, half = kq & 1;
#pragma unroll
    for (int i = 0; i < 8; i++) {
      int n = n0 + i;
      s16x4 w;
#pragma unroll
      for (int j = 0; j < 4; j++) w[j] = f2bf(i < 4 ? va[j][i] : vb[j][i - 4]);
      *(s16x4*)&bufB[buf][n * 64 + ((gc ^ (n & 7)) * 8) + half * 4] = w;
    }
  };
  auto MFMA_KS = [&](int cur, int ks) {
    bf16x8 a[8], b[4];
#pragma unroll
    for (int mi = 0; mi < 8; mi++) {
      int m = wm * 128 + mi * 16 + lm;
      a[mi] = *(const bf16x8*)&bufA[cur][m * 64 + (((ks * 4 + lg) ^ (m & 7)) * 8)];
    }
#pragma unroll
    for (int nf = 0; nf < 4; nf++) {
      int n = (nf >> 1) * 128 + wn * 32 + (nf & 1) * 16 + lm;
      b[nf] = *(const bf16x8*)&bufB[cur][n * 64 + (((ks * 4 + lg) ^ (n & 7)) * 8)];
    }
    __builtin_amdgcn_s_setprio(1);
#pragma unroll
    for (int mi = 0; mi < 8; mi++)
#pragma unroll
      for (int nf = 0; nf < 4; nf++)
        acc[mi][nf] = __builtin_amdgcn_mfma_f32_16x16x32_bf16(a[mi], b[nf], acc[mi][nf], 0, 0, 0);
    __builtin_amdgcn_s_setprio(0);
  };

  // prologue: A(0)+B(0) staged, B(1) in flight
  STAGE_A(0, 0);
  LOAD_B(0);
  WRITE_B(0);                           // compiler waits vmcnt for va/vb
  LOAD_B(1);
  asm volatile("s_waitcnt lgkmcnt(0)" ::: "memory");

  const int NT = HDIM / 64;             // 32
#pragma unroll 1
  for (int kt = 0; kt < NT; kt++) {
    int cur = kt & 1;
    if (kt + 1 < NT) {
      STAGE_A(cur ^ 1, kt + 1);
      asm volatile("s_waitcnt vmcnt(12)" ::: "memory");   // A(kt) landed
    } else {
      asm volatile("s_waitcnt vmcnt(0)" ::: "memory");
    }
    __builtin_amdgcn_s_barrier();       // bufA[cur], bufB[cur] ready
    MFMA_KS(cur, 0);
    if (kt + 1 < NT) {
      WRITE_B(cur ^ 1);                 // B(kt+1) -> other buffer, overlaps MFMA
      if (kt + 2 < NT) LOAD_B(kt + 2);
    }
    MFMA_KS(cur, 1);
    asm volatile("s_waitcnt lgkmcnt(0)" ::: "memory");
    __builtin_amdgcn_s_barrier();       // reads retired + B writes visible
  }
  // epilogue: SiLU(gate)*up -> S (bf16, granule-swizzled by rg&7 per 64 cols)
#pragma unroll
  for (int mi = 0; mi < 8; mi++)
#pragma unroll
    for (int nfg = 0; nfg < 2; nfg++)
#pragma unroll
      for (int j = 0; j < 4; j++) {
        int row = wm * 128 + mi * 16 + lg * 4 + j;
        int rg = rb + row;
        int scol = nb * 128 + wn * 32 + nfg * 16 + lm;
        int base = scol & ~63, o = scol & 63;
        int dc = (((o >> 3) ^ (rg & 7)) << 3) | (o & 7);
        float g = acc[mi][nfg][j], u = acc[mi][nfg + 2][j];
        float sv = (g / (1.f + expf(-g))) * u;
        S[(size_t)rg * IDIM + base + dc] = f2bf(sv);
      }
}

// ===== down GEMM, fused fp32 weights: 256M x 256N x BK64 ==================
__global__ __launch_bounds__(512, 2) void down_kernel(
    const short* __restrict__ S, const float* __restrict__ dw,
    const int* __restrict__ offs, short* __restrict__ Sout) {
  int nb = blockIdx.x;                  // 0..7
  int rb = blockIdx.y * 256;
  if (rb >= offs[NEXP]) return;
  int e = 0;
#pragma unroll
  for (int i = 1; i < NEXP; i++) e += (rb >= offs[i]);
  const float* Wsrc = dw + (size_t)e * IDIM * HDIM;
  const short* Ar = S + (size_t)rb * IDIM;

  __shared__ short bufA[2][256 * 64];
  __shared__ short bufB[2][256 * 64];
  int tid = threadIdx.x, lane = tid & 63, wid = tid >> 6;
  int wm = wid >> 2, wn = wid & 3;
  int lm = lane & 15, lg = lane >> 4;

  int oct = tid >> 4, kq = tid & 15;
  int n0 = oct * 8;
  const float* Bp = Wsrc + nb * 256 + n0;

  f32x4 acc[8][4];
#pragma unroll
  for (int a = 0; a < 8; a++)
#pragma unroll
    for (int b = 0; b < 4; b++) acc[a][b] = (f32x4)0.f;

  f32x4 va[4], vb[4];

  auto STAGE_A = [&](int buf, int kt) {
    int k0 = kt * 64;
#pragma unroll
    for (int it = 0; it < 4; it++) {
      int idx = tid + it * 512;
      gload_lds16(Ar + (size_t)(idx >> 3) * IDIM + k0 + (idx & 7) * 8, &bufA[buf][idx * 8]);
    }
  };
  auto LOAD_B = [&](int kt) {
    const float* p = Bp + (size_t)(kt * 64 + kq * 4) * HDIM;
#pragma unroll
    for (int j = 0; j < 4; j++) {
      va[j] = *(const f32x4*)(p + (size_t)j * HDIM);
      vb[j] = *(const f32x4*)(p + (size_t)j * HDIM + 4);
    }
  };
  auto WRITE_B = [&](int buf) {
    int gc = kq >> 1, half = kq & 1;
#pragma unroll
    for (int i = 0; i < 8; i++) {
      int n = n0 + i;
      s16x4 w;
#pragma unroll
      for (int j = 0; j < 4; j++) w[j] = f2bf(i < 4 ? va[j][i] : vb[j][i - 4]);
      *(s16x4*)&bufB[buf][n * 64 + ((gc ^ (n & 7)) * 8) + half * 4] = w;
    }
  };
  auto MFMA_KS = [&](int cur, int ks) {
    bf16x8 a[8], b[4];
#pragma unroll
    for (int mi = 0; mi < 8; mi++) {
      int m = wm * 128 + mi * 16 + lm;
      a[mi] = *(const bf16x8*)&bufA[cur][m * 64 + (((ks * 4 + lg) ^ (m & 7)) * 8)];
    }
#pragma unroll
    for (int nf = 0; nf < 4; nf++) {
      int n = wn * 64 + nf * 16 + lm;
      b[nf] = *(const bf16x8*)&bufB[cur][n * 64 + (((ks * 4 + lg) ^ (n & 7)) * 8)];
    }
    __builtin_amdgcn_s_setprio(1);
#pragma unroll
    for (int mi = 0; mi < 8; mi++)
#pragma unroll
      for (int nf = 0; nf < 4; nf++)
        acc[mi][nf] = __builtin_amdgcn_mfma_f32_16x16x32_bf16(a[mi], b[nf], acc[mi][nf], 0, 0, 0);
    __builtin_amdgcn_s_setprio(0);
  };

  STAGE_A(0, 0);
  LOAD_B(0);
  WRITE_B(0);
  LOAD_B(1);
  asm volatile("s_waitcnt lgkmcnt(0)" ::: "memory");

  const int NT = IDIM / 64;             // 22
#pragma unroll 1
  for (int kt = 0; kt < NT; kt++) {
    int cur = kt & 1;
    if (kt + 1 < NT) {
      STAGE_A(cur ^ 1, kt + 1);
      asm volatile("s_waitcnt vmcnt(12)" ::: "memory");
    } else {
      asm volatile("s_waitcnt vmcnt(0)" ::: "memory");
    }
    __builtin_amdgcn_s_barrier();
    MFMA_KS(cur, 0);
    if (kt + 1 < NT) {
      WRITE_B(cur ^ 1);
      if (kt + 2 < NT) LOAD_B(kt + 2);
    }
    MFMA_KS(cur, 1);
    asm volatile("s_waitcnt lgkmcnt(0)" ::: "memory");
    __builtin_amdgcn_s_barrier();
  }
  // epilogue: plain bf16 stores (combine does the weighted sum)
#pragma unroll
  for (int mi = 0; mi < 8; mi++)
#pragma unroll
    for (int nf = 0; nf < 4; nf++)
#pragma unroll
      for (int j = 0; j < 4; j++) {
        int row = wm * 128 + mi * 16 + lg * 4 + j;
        int col = nb * 256 + wn * 64 + nf * 16 + lm;
        Sout[(size_t)(rb + row) * HDIM + col] = f2bf(acc[mi][nf][j]);
      }
}

// ------------- combine: out[t] = w1*Sout[r1] + w2*Sout[r2] ---------------
__global__ __launch_bounds__(256) void combine_kernel(
    const short* __restrict__ Sout, const int* __restrict__ tok2row,
    const float* __restrict__ row_weight, float* __restrict__ out) {
  int t = blockIdx.x;
  int r1 = tok2row[2 * t], r2 = tok2row[2 * t + 1];
  float w1 = row_weight[r1], w2 = row_weight[r2];
  int c = threadIdx.x * 8;
  s16x8 a = *(const s16x8*)&Sout[(size_t)r1 * HDIM + c];
  s16x8 b = *(const s16x8*)&Sout[(size_t)r2 * HDIM + c];
  float* o = out + (size_t)t * HDIM + c;
#pragma unroll
  for (int j = 0; j < 8; j++) o[j] = w1 * bf2f(a[j]) + w2 * bf2f(b[j]);
}

extern "C" void kernel_launch(void* const* d_in, const int* in_sizes, int n_in,
                              void* d_out, int out_size, void* d_ws, size_t ws_size,
                              hipStream_t stream) {
  const float* hs  = (const float*)d_in[0];
  const float* rw  = (const float*)d_in[1];
  const float* guw = (const float*)d_in[2];
  const float* dw  = (const float*)d_in[3];
  float* out = (float*)d_out;

  char* ws = (char*)d_ws;
  size_t off = 0;
  auto take = [&](size_t b) { size_t p = off; off = (off + b + 255) & ~(size_t)255; return p; };
  size_t s_off      = take((size_t)RPAD * IDIM * 2);   // 17.3 MB
  int*   counts     = (int*)(ws + take(32 * 4));
  int*   offs       = (int*)(ws + take(16 * 4));
  int*   pair_e     = (int*)(ws + take(NPAIR * 4));
  float* pair_w     = (float*)(ws + take(NPAIR * 4));
  int*   pair_pos   = (int*)(ws + take(NPAIR * 4));
  int*   row_token  = (int*)(ws + take(RPAD * 4));
  float* row_weight = (float*)(ws + take(RPAD * 4));
  int*   tok2row    = (int*)(ws + take(NPAIR * 4));
  size_t ac_off     = take((size_t)RPAD * HDIM * 2);   // 25.2 MB
  size_t sout_off   = take((size_t)RPAD * HDIM * 2);   // 25.2 MB

  short* S    = (short*)(ws + s_off);
  short* A_c  = (short*)(ws + ac_off);
  short* Sout = (short*)(ws + sout_off);

  hipMemsetAsync(counts, 0, 32 * 4, stream);
  hipMemsetAsync(row_token, 0xFF, RPAD * 4, stream);

  router_kernel<<<T_TOK / 4, 256, 0, stream>>>(hs, rw, pair_e, pair_w, pair_pos, counts);
  prefix_kernel<<<1, 64, 0, stream>>>(counts, offs);
  rowmap_kernel<<<NPAIR / 256, 256, 0, stream>>>(pair_e, pair_w, pair_pos, offs,
                                                 row_token, row_weight, tok2row);
  gather_kernel<<<RPAD, 256, 0, stream>>>(hs, row_token, A_c);

  gateup_kernel<<<dim3(11, RPAD / 256), 512, 0, stream>>>(A_c, guw, offs, S);
  down_kernel<<<dim3(8, RPAD / 256), 512, 0, stream>>>(S, dw, offs, Sout);
  combine_kernel<<<T_TOK, 256, 0, stream>>>(Sout, tok2row, row_weight, out);
}